// Round 4
// baseline (311.526 us; speedup 1.0000x reference)
//
#include <hip/hip_runtime.h>
#include <hip/hip_bf16.h>

// Swin window MHSA, MI355X, round 10.
//   k_prep : Aext[2176x256]=G'(+w1/w2 rows), Wov3[256x2048], cvec, relL2(+c0)
//   k_conv : X fp32 -> rolled bf16 Xroll[n][3200][256]  (coalesced stores)
//   k_gemm1: M_T[t][a'] = Xroll . Aext^T
//            R10: NO LDS, NO BARRIERS. Xroll_n (1.6MB) is L2-resident
//            (R9 FETCH=17MB ~= compulsory proves it), so LDS staging was
//            pure skeleton overhead (R8/R9 both pinned at 60us with ~94%
//            idle per tile). Each wave streams B direct L2->reg (full-line
//            coalesced), A-slice in areg[8][4], waves free-run; compiler
//            emits fine-grained vmcnt per breg group. 2 waves/SIMD in
//            anti-phase hide L2 latency under each other's MFMAs.
//   k_attn2: per (n,window): S=Xp.M, softmax, T=X.wmap; T overwrites M in-place
//   k_gemm3: out[o][t] = Wov3 . T_T^T + cvec  -- 128x128, BK=128, DMA fills

#define NBATCH 8
#define MSTR   2176           // M_T / T_T row stride (a'-dim, 17 tiles of 128)
#define TROWS  3200           // padded token rows (50 tiles of 64)

typedef unsigned short ushort_t;
typedef __attribute__((ext_vector_type(8))) short bf16x8;   // 8 bf16 = 4 VGPR
typedef __attribute__((ext_vector_type(8))) unsigned short u16x8;
typedef __attribute__((ext_vector_type(4))) float f32x4;    // MFMA acc

__device__ __forceinline__ float b2f(ushort_t u) {
  union { unsigned int i; float f; } v; v.i = ((unsigned int)u) << 16; return v.f;
}
__device__ __forceinline__ ushort_t f2b(float f) {
  union { float f; unsigned int u; } v; v.f = f;
  unsigned int u = v.u;
  return (ushort_t)((u + 0x7FFFu + ((u >> 16) & 1u)) >> 16);
}
__device__ __forceinline__ int regof(int y) { return (y < 49) ? 0 : ((y < 53) ? 1 : 2); }
__device__ __forceinline__ int div7(int t) { return (t * 37) >> 8; }  // t/7, t<64
__device__ __forceinline__ int tmap(int p, int gi, int gj) {
  int wi = div7(p); return (gi * 7 + wi) * 56 + gj * 7 + (p - wi * 7);
}
__device__ __forceinline__ ushort4 pack4(f32x4 a) {
  ushort4 u; u.x = f2b(a[0]); u.y = f2b(a[1]); u.z = f2b(a[2]); u.w = f2b(a[3]);
  return u;
}
// async global->LDS, 16B per lane; lds dest must be wave-uniform base
__device__ __forceinline__ void gload_lds16(const ushort_t* g, ushort_t* l) {
  __builtin_amdgcn_global_load_lds(
      (const __attribute__((address_space(1))) void*)g,
      (__attribute__((address_space(3))) void*)l, 16, 0, 0);
}
__device__ __forceinline__ void sb0() { __builtin_amdgcn_sched_barrier(0); }

// ================= prep (unchanged) =================
__global__ void k_prep(const float* __restrict__ Wk, const float* __restrict__ Wq,
                       const float* __restrict__ Wo, const float* __restrict__ Wv,
                       const float* __restrict__ bk, const float* __restrict__ bq,
                       const float* __restrict__ bv, const float* __restrict__ bo,
                       const float* __restrict__ relc,
                       ushort_t* __restrict__ Aext, ushort_t* __restrict__ Wov3,
                       float* __restrict__ cvec, float* __restrict__ relL2) {
  __shared__ float red[8];
  int blk = blockIdx.x, t = threadIdx.x;
  if (blk < 512) {
    int h = blk >> 6, b0 = (blk & 63) << 2, a = t;
    const float* wkh = Wk + h * 65536;
    const float* wqh = Wq + h * 65536;
    float a0 = 0.f, a1 = 0.f, a2 = 0.f, a3 = 0.f;
    for (int dd = 0; dd < 256; ++dd) {
      float wk = wkh[dd * 256 + a];
      float4 w4 = *(const float4*)(wqh + dd * 256 + b0);
      a0 += wk * w4.x; a1 += wk * w4.y; a2 += wk * w4.z; a3 += wk * w4.w;
    }
    ushort4 u; u.x = f2b(a0); u.y = f2b(a1); u.z = f2b(a2); u.w = f2b(a3);
    *(ushort4*)(Aext + (h * 256 + a) * 256 + b0) = u;
  } else if (blk < 1024) {
    int bb = blk - 512;
    int h = bb >> 6, o0 = (bb & 63) << 2, d = t;
    float a0 = 0.f, a1 = 0.f, a2 = 0.f, a3 = 0.f;
    for (int dd = 0; dd < 256; ++dd) {
      float wv = Wv[(h * 256 + dd) * 256 + d];
      a0 += Wo[(o0 + 0) * 2048 + h * 256 + dd] * wv;
      a1 += Wo[(o0 + 1) * 2048 + h * 256 + dd] * wv;
      a2 += Wo[(o0 + 2) * 2048 + h * 256 + dd] * wv;
      a3 += Wo[(o0 + 3) * 2048 + h * 256 + dd] * wv;
    }
    Wov3[(o0 + 0) * 2048 + h * 256 + d] = f2b(a0);
    Wov3[(o0 + 1) * 2048 + h * 256 + d] = f2b(a1);
    Wov3[(o0 + 2) * 2048 + h * 256 + d] = f2b(a2);
    Wov3[(o0 + 3) * 2048 + h * 256 + d] = f2b(a3);
  } else if (blk < 1032) {
    int h = blk - 1024;
    float s1 = 0.f, s2 = 0.f;
    for (int dd = 0; dd < 256; ++dd) {
      s1 += bk[h * 256 + dd] * Wq[(h * 256 + dd) * 256 + t];
      s2 += bq[h * 256 + dd] * Wk[(h * 256 + dd) * 256 + t];
    }
    Aext[(2048 + h) * 256 + t] = f2b(s1);
    Aext[(2056 + h) * 256 + t] = f2b(s2);
  } else if (blk == 1032) {
    for (int i = t; i < 112 * 256 / 8; i += 256)
      *(u16x8*)(Aext + 2064 * 256 + i * 8) = (u16x8){0,0,0,0,0,0,0,0};
  } else if (blk < 1289) {
    int o = blk - 1033;
    const float* wob = Wo + o * 2048;
    float acc = 0.f;
#pragma unroll
    for (int j = 0; j < 8; ++j) acc += wob[j * 256 + t] * bv[j * 256 + t];
#pragma unroll
    for (int s = 1; s < 64; s <<= 1) acc += __shfl_xor(acc, s);
    if ((t & 63) == 0) red[t >> 6] = acc;
    __syncthreads();
    if (t == 0) cvec[o] = bo[o] + red[0] + red[1] + red[2] + red[3];
  } else {
    if (t < 8) {
      float c = 0.f;
      for (int dd = 0; dd < 256; ++dd) c += bk[t * 256 + dd] * bq[t * 256 + dd];
      red[t] = c * 0.0625f;
    }
    __syncthreads();
    for (int i = t; i < 8 * 169; i += 256) {
      int h = i / 169, idx = i - h * 169;
      relL2[i] = relc[idx * 8 + h] + red[h];
    }
  }
}

// ================= conv: rolled gather, coalesced bf16 stores =============
__global__ void k_conv(const float* __restrict__ X, ushort_t* __restrict__ Xroll) {
  const int n = blockIdx.x / 57, y = blockIdx.x % 57;
  ushort_t* xr = Xroll + (size_t)n * TROWS * 256;
  const int d = threadIdx.x;
  if (y == 56) {  // zero pad rows 3136..3199
    for (int i = d; i < 64 * 256 / 8; i += 256)
      *(u16x8*)(xr + 3136 * 256 + i * 8) = (u16x8){0,0,0,0,0,0,0,0};
    return;
  }
  const int c = d >> 4, p1 = (d >> 2) & 3, p2 = d & 3;
  const int sp = c * 16 + (((p1 + 1) & 3) << 2) + ((p2 + 1) & 3);
  const int ty = (p1 == 3) ? y : ((y == 0) ? 55 : y - 1);
  const float* rowp = X + (size_t)n * 256 * 3136 + sp * 3136 + ty * 56;
  ushort_t* orow = xr + y * 56 * 256 + d;
  for (int x = 0; x < 56; ++x) {
    int tx = (p2 == 3) ? x : ((x == 0) ? 55 : x - 1);
    orow[x * 256] = f2b(rowp[tx]);   // 256 lanes -> 512B contiguous store
  }
}

// ================= gemm1: M_T[t][a'] = Xroll . Aext^T =====================
// R10: barrier-free, LDS-free. Block = (n = XCD, aa, chunk c of 7); wave
// (wa,wt) owns 64a x 32t per 64-row tile.
//   - areg[8][4] (128 VGPR): A-slice rows [a0+wa*64,+64), full K.
//   - per tile: 16 global bf16x8 loads of B direct from L2 (Xroll_n is
//     L2-resident; full 64B-line coalescing: quad*16B x l16 rows), sb0,
//     then 64 MFMAs with compiler-placed fine-grained vmcnt waits.
//   - waves free-run: no __syncthreads, no vmcnt drains, no DMA queue.
__global__ __launch_bounds__(256, 2) void k_gemm1(
    const ushort_t* __restrict__ Xroll, const ushort_t* __restrict__ Aext,
    ushort_t* __restrict__ MT) {
  const int bx0 = blockIdx.x;
  const int n = bx0 & 7;                  // XCD-bijective: XCD k owns batch k
  const int inner = bx0 >> 3;             // 0..118
  const int aa = inner % 17;
  const int c  = inner / 17;              // chunk 0..6
  const int a0 = aa * 128;
  const int tstart = (c == 0) ? 0 : (7 * c + 1);  // in 64-row tiles
  const int T = (c == 0) ? 8 : 7;                 // 8 + 6x7 = 50 tiles
  const int tid = threadIdx.x, wave = tid >> 6, lane = tid & 63;
  const int quad = lane >> 4, l16 = lane & 15;
  const int wa = wave >> 1, wt = wave & 1;
  const ushort_t* Xn = Xroll + (size_t)n * TROWS * 256;
  ushort_t* Mn = MT + (size_t)n * TROWS * MSTR;

  // ---- A-slice into regs: wave owns rows [a0+wa*64, +64), full K ----
  const ushort_t* abase = Aext + (size_t)(a0 + wa * 64 + l16) * 256 + quad * 8;
  bf16x8 areg[8][4];
#pragma unroll
  for (int kk = 0; kk < 8; ++kk)
#pragma unroll
    for (int i = 0; i < 4; ++i)
      areg[kk][i] = *(const bf16x8*)(abase + i * 4096 + kk * 32);   // 32 loads
  sb0();

  // B rows for this wave: tb + wt*32 + j*16 + l16, 16B chunk quad*8
  const ushort_t* bbase =
      Xn + (size_t)(tstart * 64 + wt * 32 + l16) * 256 + quad * 8;

  for (int m = 0; m < T; ++m) {
    const ushort_t* bsrc = bbase + (size_t)m * 64 * 256;
    bf16x8 breg[8][2];
#pragma unroll
    for (int kk = 0; kk < 8; ++kk)
#pragma unroll
      for (int j = 0; j < 2; ++j)
        breg[kk][j] = *(const bf16x8*)(bsrc + j * 16 * 256 + kk * 32);
    sb0();   // keep all 16 loads issued before MFMAs (latency pipelines)

    f32x4 acc[4][2];
#pragma unroll
    for (int i = 0; i < 4; ++i)
#pragma unroll
      for (int j = 0; j < 2; ++j) acc[i][j] = (f32x4){0.f, 0.f, 0.f, 0.f};
#pragma unroll
    for (int kk = 0; kk < 8; ++kk)
#pragma unroll
      for (int i = 0; i < 4; ++i)
#pragma unroll
        for (int j = 0; j < 2; ++j)
          acc[i][j] = __builtin_amdgcn_mfma_f32_16x16x32_bf16(areg[kk][i], breg[kk][j], acc[i][j], 0, 0, 0);

    const int tb = (tstart + m) * 64;
#pragma unroll
    for (int i = 0; i < 4; ++i)
#pragma unroll
      for (int j = 0; j < 2; ++j) {
        int tg = tb + wt * 32 + j * 16 + l16;
        int ag = a0 + wa * 64 + i * 16 + quad * 4;
        *(ushort4*)(Mn + (size_t)tg * MSTR + ag) = pack4(acc[i][j]);
      }
  }
}

// ================= attn2 (unchanged) ==============================
#define XP_STR 264
__global__ __launch_bounds__(512, 4) void k_attn2(
    const ushort_t* __restrict__ Xroll, ushort_t* __restrict__ MT,
    const float* __restrict__ relL2) {
  __shared__ ushort_t Xp[64 * XP_STR];
  __shared__ ushort_t StB[2][64 * 72];
  __shared__ float aqsL[8 * 64];
  __shared__ float bpsL[8 * 64];
  __shared__ float relLh[8 * 169];

  const int tid = threadIdx.x;
  const int wave = tid >> 6, lane = tid & 63;
  const int quad = lane >> 4, l16 = lane & 15;
  const int group = wave >> 2, wv = wave & 3;
  const int n = blockIdx.x >> 6, g = blockIdx.x & 63;
  const int gi = g >> 3, gj = g & 7;
  const ushort_t* Xn = Xroll + (size_t)n * TROWS * 256;
  ushort_t* Mn = MT + (size_t)n * TROWS * MSTR;

  {
    const int p = tid & 63, cg = tid >> 6;
    if (p < 49) {
      int t = tmap(p, gi, gj);
#pragma unroll
      for (int i = 0; i < 4; ++i)
        *(u16x8*)(&Xp[p * XP_STR + (cg * 4 + i) * 8]) =
            *(const u16x8*)(Xn + t * 256 + (cg * 4 + i) * 8);
    } else {
#pragma unroll
      for (int i = 0; i < 4; ++i)
        *(u16x8*)(&Xp[p * XP_STR + (cg * 4 + i) * 8]) = (u16x8){0,0,0,0,0,0,0,0};
    }
  }
  for (int i = tid; i < 8 * 169; i += 512) relLh[i] = relL2[i];
  {
    const int h = tid >> 6, q = tid & 63;
    int qq = (q < 49) ? q : 48;
    int t = tmap(qq, gi, gj);
    aqsL[h * 64 + q] = b2f(Mn[(size_t)t * MSTR + 2048 + h]);
    bpsL[h * 64 + q] = b2f(Mn[(size_t)t * MSTR + 2056 + h]);
  }
  __syncthreads();

  bf16x8 xfr[4][2];
#pragma unroll
  for (int dt = 0; dt < 4; ++dt) {
    const int d = (wv * 4 + dt) * 16 + l16;
#pragma unroll
    for (int kk = 0; kk < 2; ++kk)
#pragma unroll
      for (int j = 0; j < 8; ++j)
        xfr[dt][kk][j] = (short)Xp[(kk * 32 + quad * 8 + j) * XP_STR + d];
  }

  const int q = wv * 16 + l16;
  const int qq = (q < 49) ? q : 48;
  const int tq = tmap(qq, gi, gj);
  const ushort_t* Mbase = Mn + (size_t)tq * MSTR + quad * 8;
  const int yq = div7(qq), xq = qq - yq * 7;
  const int fq = regof(gi * 7 + yq) * 3 + regof(gj * 7 + xq);

  for (int hh = 0; hh < 4; ++hh) {
    const int h = hh * 2 + group;
    f32x4 sacc[4];
#pragma unroll
    for (int pt = 0; pt < 4; ++pt) sacc[pt] = (f32x4){0.f, 0.f, 0.f, 0.f};
    const ushort_t* mrow = Mbase + h * 256;
#pragma unroll
    for (int kk = 0; kk < 8; ++kk) {
      bf16x8 bfm = *(const bf16x8*)(mrow + kk * 32);
#pragma unroll
      for (int pt = 0; pt < 4; ++pt) {
        bf16x8 af = *(const bf16x8*)(&Xp[(pt * 16 + l16) * XP_STR + kk * 32 + quad * 8]);
        sacc[pt] = __builtin_amdgcn_mfma_f32_16x16x32_bf16(af, bfm, sacc[pt], 0, 0, 0);
      }
    }
    float v[16];
    const float aqv = aqsL[h * 64 + q];
    const float* rel_h = &relLh[h * 169];
    float m = -1e30f;
#pragma unroll
    for (int pt = 0; pt < 4; ++pt)
#pragma unroll
      for (int r = 0; r < 4; ++r) {
        int p = pt * 16 + quad * 4 + r;
        float val = -1e30f;
        if (p < 49) {
          int yp = div7(p), xp = p - yp * 7;
          int fp = regof(gi * 7 + yp) * 3 + regof(gj * 7 + xp);
          val = (sacc[pt][r] + aqv + bpsL[h * 64 + p]) * 0.0625f +
                rel_h[(yp - yq + 6) + 13 * (xp - xq + 6)];
          if (fp != fq) val -= 100.f;
        }
        v[pt * 4 + r] = val;
        m = fmaxf(m, val);
      }
    m = fmaxf(m, __shfl_xor(m, 16));
    m = fmaxf(m, __shfl_xor(m, 32));
    float s = 0.f;
#pragma unroll
    for (int i = 0; i < 16; ++i) { v[i] = __expf(v[i] - m); s += v[i]; }
    s += __shfl_xor(s, 16);
    s += __shfl_xor(s, 32);
    const float inv = 1.f / s;
    __syncthreads();
    {
      ushort_t* sb = &StB[group][q * 72];
#pragma unroll
      for (int pt = 0; pt < 4; ++pt) {
        ushort4 u;
        u.x = f2b(v[pt * 4 + 0] * inv); u.y = f2b(v[pt * 4 + 1] * inv);
        u.z = f2b(v[pt * 4 + 2] * inv); u.w = f2b(v[pt * 4 + 3] * inv);
        *(ushort4*)(&sb[pt * 16 + quad * 4]) = u;
      }
    }
    __syncthreads();
#pragma unroll
    for (int qt = 0; qt < 4; ++qt) {
      f32x4 tacc[4];
#pragma unroll
      for (int dt = 0; dt < 4; ++dt) tacc[dt] = (f32x4){0.f, 0.f, 0.f, 0.f};
#pragma unroll
      for (int kk = 0; kk < 2; ++kk) {
        bf16x8 bfw = *(const bf16x8*)(&StB[group][(qt * 16 + l16) * 72 + kk * 32 + quad * 8]);
#pragma unroll
        for (int dt = 0; dt < 4; ++dt)
          tacc[dt] = __builtin_amdgcn_mfma_f32_16x16x32_bf16(xfr[dt][kk], bfw, tacc[dt], 0, 0, 0);
      }
      int q2 = qt * 16 + l16;
      if (q2 < 49) {
        int t2 = tmap(q2, gi, gj);
#pragma unroll
        for (int dt = 0; dt < 4; ++dt) {
          int d0 = (wv * 4 + dt) * 16 + quad * 4;
          *(ushort4*)(Mn + (size_t)t2 * MSTR + h * 256 + d0) = pack4(tacc[dt]);
        }
      }
    }
  }
}

// ================= gemm3: out[o][t] = Wov3 . T_T^T + cvec =================
// 128o x 128t tile, BK=128, 16 k-iters, DMA fills with XOR swizzle.
__global__ __launch_bounds__(256, 2) void k_gemm3(
    const ushort_t* __restrict__ Wov3, const ushort_t* __restrict__ MT,
    const float* __restrict__ cvec, float* __restrict__ out) {
  __shared__ ushort_t Asm[128 * 128];   // 32 KB
  __shared__ ushort_t Bsm[128 * 128];   // 32 KB
  const int bx0 = blockIdx.x;
  const int bx = (bx0 & 7) * 50 + (bx0 >> 3);    // bijective: 400 = 8*50
  const int n = bx / 50, r2 = bx % 50;
  const int oi = r2 / 25, tt = r2 % 25;
  const int o0 = oi * 128, t0 = tt * 128;
  const int tid = threadIdx.x, wave = tid >> 6, lane = tid & 63;
  const int quad = lane >> 4, l16 = lane & 15;
  const int wa = wave >> 1, wt = wave & 1;
  const ushort_t* Tn = MT + (size_t)n * TROWS * MSTR;
  float* on = out + (size_t)n * 256 * 3136;
  const int sw = l16 & 7;

  f32x4 acc[4][4];
#pragma unroll
  for (int i = 0; i < 4; ++i)
#pragma unroll
    for (int j = 0; j < 4; ++j) acc[i][j] = (f32x4){0.f, 0.f, 0.f, 0.f};

  for (int kit = 0; kit < 16; ++kit) {
    const int kb = kit * 128;
    // fill A[128][128] and B[128][128], 16B chunks, swizzle c^=(r&7)
#pragma unroll
    for (int i = 0; i < 8; ++i) {
      int S = i * 256 + tid;
      int rr = S >> 4, sc = S & 15;
      int c = (sc & 8) | ((sc ^ rr) & 7);
      gload_lds16(Wov3 + (o0 + rr) * 2048 + kb + c * 8,
                  &Asm[(i * 256 + wave * 64) * 8]);
    }
#pragma unroll
    for (int i = 0; i < 8; ++i) {
      int S = i * 256 + tid;
      int rr = S >> 4, sc = S & 15;
      int c = (sc & 8) | ((sc ^ rr) & 7);
      gload_lds16(Tn + (size_t)(t0 + rr) * MSTR + kb + c * 8,
                  &Bsm[(i * 256 + wave * 64) * 8]);
    }
    __syncthreads();
#pragma unroll
    for (int kk = 0; kk < 4; ++kk) {
      bf16x8 af[4], bf[4];
      const int c = kk * 4 + quad;
      const int pos = (c & 8) | ((c ^ sw) & 7);
#pragma unroll
      for (int i = 0; i < 4; ++i)
        af[i] = *(const bf16x8*)(&Asm[(wa * 64 + i * 16 + l16) * 128 + pos * 8]);
#pragma unroll
      for (int j = 0; j < 4; ++j)
        bf[j] = *(const bf16x8*)(&Bsm[(wt * 64 + j * 16 + l16) * 128 + pos * 8]);
#pragma unroll
      for (int i = 0; i < 4; ++i)
#pragma unroll
        for (int j = 0; j < 4; ++j)
          acc[i][j] = __builtin_amdgcn_mfma_f32_16x16x32_bf16(af[i], bf[j], acc[i][j], 0, 0, 0);
    }
    __syncthreads();
  }
  // epilogue: + cvec, guard pad tokens (regular stores -> L2 write-combining)
#pragma unroll
  for (int i = 0; i < 4; ++i) {
    const int ob = o0 + wa * 64 + i * 16 + quad * 4;
    const float4 cv = *(const float4*)(cvec + ob);
#pragma unroll
    for (int j = 0; j < 4; ++j) {
      const int tg = t0 + wt * 64 + j * 16 + l16;
      if (tg < 3136) {
        on[(size_t)(ob + 0) * 3136 + tg] = acc[i][j][0] + cv.x;
        on[(size_t)(ob + 1) * 3136 + tg] = acc[i][j][1] + cv.y;
        on[(size_t)(ob + 2) * 3136 + tg] = acc[i][j][2] + cv.z;
        on[(size_t)(ob + 3) * 3136 + tg] = acc[i][j][3] + cv.w;
      }
    }
  }
}

extern "C" void kernel_launch(void* const* d_in, const int* in_sizes, int n_in,
                              void* d_out, int out_size, void* d_ws, size_t ws_size,
                              hipStream_t stream) {
  (void)in_sizes; (void)n_in; (void)out_size; (void)ws_size;
  const float* X  = (const float*)d_in[0];
  const float* Wk = (const float*)d_in[1];
  const float* bk = (const float*)d_in[2];
  const float* Wq = (const float*)d_in[3];
  const float* bq = (const float*)d_in[4];
  const float* Wv = (const float*)d_in[5];
  const float* bv = (const float*)d_in[6];
  const float* Wo = (const float*)d_in[7];
  const float* bo = (const float*)d_in[8];
  const float* rc = (const float*)d_in[9];

  ushort_t* MT    = (ushort_t*)d_ws;                       // 8*3200*2176 u16
  ushort_t* Xroll = MT + (size_t)8 * TROWS * MSTR;         // 8*3200*256 u16
  ushort_t* Aext  = Xroll + (size_t)8 * TROWS * 256;       // 2176*256 u16
  ushort_t* Wov3  = Aext + 2176 * 256;                     // 256*2048 u16
  float* fbase = (float*)(Wov3 + 256 * 2048);
  float* cvec  = fbase;         // 256 f32
  float* relL2 = fbase + 256;   // 8*169 f32
  float* out = (float*)d_out;

  k_prep <<<dim3(1290), dim3(256), 0, stream>>>(Wk, Wq, Wo, Wv, bk, bq, bv, bo, rc,
                                                Aext, Wov3, cvec, relL2);
  k_conv <<<dim3(8 * 57), dim3(256), 0, stream>>>(X, Xroll);
  k_gemm1<<<dim3(8 * 119), dim3(256), 0, stream>>>(Xroll, Aext, MT);
  k_attn2<<<dim3(8 * 64), dim3(512), 0, stream>>>(Xroll, MT, relL2);
  k_gemm3<<<dim3(8 * 50), dim3(256), 0, stream>>>(Wov3, MT, cvec, out);
}

// Round 5
// 305.205 us; speedup vs baseline: 1.0207x; 1.0207x over previous
//
#include <hip/hip_runtime.h>
#include <hip/hip_bf16.h>

// Swin window MHSA, MI355X, round 11.
//   k_prep : Aext[2176x256]=G'(+w1/w2 rows), Wov3[256x2048], cvec, relL2(+c0)
//   k_conv : X fp32 -> rolled bf16 Xroll[n][3200][256]  (coalesced stores)
//   k_fused: per (n,window) block: M=G'.X (LDS), S=Xp.M, softmax, T^T=X^T.w,
//            out += Wov3_h . T^T  -- replaces gemm1+attn2+gemm3. MT (111MB)
//            never touches HBM: kills ~420MB of HBM round-trips that pinned
//            the old chain at ~160us (R8-R10: every gemm1 schedule hit the
//            same wall; dataflow was the problem, not the schedule).
//            Weights (Aext+Wov3, 2.1MB) are per-XCD L2-resident (n = XCD).

#define NBATCH 8
#define TROWS  3200           // padded token rows
#define FSTR   264            // LDS row stride for Xp/Msm/Tsm (bank-spread)

typedef unsigned short ushort_t;
typedef __attribute__((ext_vector_type(8))) short bf16x8;   // 8 bf16 = 4 VGPR
typedef __attribute__((ext_vector_type(8))) unsigned short u16x8;
typedef __attribute__((ext_vector_type(4))) float f32x4;    // MFMA acc

__device__ __forceinline__ float b2f(ushort_t u) {
  union { unsigned int i; float f; } v; v.i = ((unsigned int)u) << 16; return v.f;
}
__device__ __forceinline__ ushort_t f2b(float f) {
  union { float f; unsigned int u; } v; v.f = f;
  unsigned int u = v.u;
  return (ushort_t)((u + 0x7FFFu + ((u >> 16) & 1u)) >> 16);
}
__device__ __forceinline__ int regof(int y) { return (y < 49) ? 0 : ((y < 53) ? 1 : 2); }
__device__ __forceinline__ int div7(int t) { return (t * 37) >> 8; }  // t/7, t<64
__device__ __forceinline__ int tmap(int p, int gi, int gj) {
  int wi = div7(p); return (gi * 7 + wi) * 56 + gj * 7 + (p - wi * 7);
}
__device__ __forceinline__ ushort4 pack4(f32x4 a) {
  ushort4 u; u.x = f2b(a[0]); u.y = f2b(a[1]); u.z = f2b(a[2]); u.w = f2b(a[3]);
  return u;
}

// ================= prep (unchanged) =================
__global__ void k_prep(const float* __restrict__ Wk, const float* __restrict__ Wq,
                       const float* __restrict__ Wo, const float* __restrict__ Wv,
                       const float* __restrict__ bk, const float* __restrict__ bq,
                       const float* __restrict__ bv, const float* __restrict__ bo,
                       const float* __restrict__ relc,
                       ushort_t* __restrict__ Aext, ushort_t* __restrict__ Wov3,
                       float* __restrict__ cvec, float* __restrict__ relL2) {
  __shared__ float red[8];
  int blk = blockIdx.x, t = threadIdx.x;
  if (blk < 512) {
    int h = blk >> 6, b0 = (blk & 63) << 2, a = t;
    const float* wkh = Wk + h * 65536;
    const float* wqh = Wq + h * 65536;
    float a0 = 0.f, a1 = 0.f, a2 = 0.f, a3 = 0.f;
    for (int dd = 0; dd < 256; ++dd) {
      float wk = wkh[dd * 256 + a];
      float4 w4 = *(const float4*)(wqh + dd * 256 + b0);
      a0 += wk * w4.x; a1 += wk * w4.y; a2 += wk * w4.z; a3 += wk * w4.w;
    }
    ushort4 u; u.x = f2b(a0); u.y = f2b(a1); u.z = f2b(a2); u.w = f2b(a3);
    *(ushort4*)(Aext + (h * 256 + a) * 256 + b0) = u;
  } else if (blk < 1024) {
    int bb = blk - 512;
    int h = bb >> 6, o0 = (bb & 63) << 2, d = t;
    float a0 = 0.f, a1 = 0.f, a2 = 0.f, a3 = 0.f;
    for (int dd = 0; dd < 256; ++dd) {
      float wv = Wv[(h * 256 + dd) * 256 + d];
      a0 += Wo[(o0 + 0) * 2048 + h * 256 + dd] * wv;
      a1 += Wo[(o0 + 1) * 2048 + h * 256 + dd] * wv;
      a2 += Wo[(o0 + 2) * 2048 + h * 256 + dd] * wv;
      a3 += Wo[(o0 + 3) * 2048 + h * 256 + dd] * wv;
    }
    Wov3[(o0 + 0) * 2048 + h * 256 + d] = f2b(a0);
    Wov3[(o0 + 1) * 2048 + h * 256 + d] = f2b(a1);
    Wov3[(o0 + 2) * 2048 + h * 256 + d] = f2b(a2);
    Wov3[(o0 + 3) * 2048 + h * 256 + d] = f2b(a3);
  } else if (blk < 1032) {
    int h = blk - 1024;
    float s1 = 0.f, s2 = 0.f;
    for (int dd = 0; dd < 256; ++dd) {
      s1 += bk[h * 256 + dd] * Wq[(h * 256 + dd) * 256 + t];
      s2 += bq[h * 256 + dd] * Wk[(h * 256 + dd) * 256 + t];
    }
    Aext[(2048 + h) * 256 + t] = f2b(s1);
    Aext[(2056 + h) * 256 + t] = f2b(s2);
  } else if (blk == 1032) {
    for (int i = t; i < 112 * 256 / 8; i += 256)
      *(u16x8*)(Aext + 2064 * 256 + i * 8) = (u16x8){0,0,0,0,0,0,0,0};
  } else if (blk < 1289) {
    int o = blk - 1033;
    const float* wob = Wo + o * 2048;
    float acc = 0.f;
#pragma unroll
    for (int j = 0; j < 8; ++j) acc += wob[j * 256 + t] * bv[j * 256 + t];
#pragma unroll
    for (int s = 1; s < 64; s <<= 1) acc += __shfl_xor(acc, s);
    if ((t & 63) == 0) red[t >> 6] = acc;
    __syncthreads();
    if (t == 0) cvec[o] = bo[o] + red[0] + red[1] + red[2] + red[3];
  } else {
    if (t < 8) {
      float c = 0.f;
      for (int dd = 0; dd < 256; ++dd) c += bk[t * 256 + dd] * bq[t * 256 + dd];
      red[t] = c * 0.0625f;
    }
    __syncthreads();
    for (int i = t; i < 8 * 169; i += 256) {
      int h = i / 169, idx = i - h * 169;
      relL2[i] = relc[idx * 8 + h] + red[h];
    }
  }
}

// ================= conv: rolled gather, coalesced bf16 stores =============
__global__ void k_conv(const float* __restrict__ X, ushort_t* __restrict__ Xroll) {
  const int n = blockIdx.x / 57, y = blockIdx.x % 57;
  ushort_t* xr = Xroll + (size_t)n * TROWS * 256;
  const int d = threadIdx.x;
  if (y == 56) {  // zero pad rows 3136..3199
    for (int i = d; i < 64 * 256 / 8; i += 256)
      *(u16x8*)(xr + 3136 * 256 + i * 8) = (u16x8){0,0,0,0,0,0,0,0};
    return;
  }
  const int c = d >> 4, p1 = (d >> 2) & 3, p2 = d & 3;
  const int sp = c * 16 + (((p1 + 1) & 3) << 2) + ((p2 + 1) & 3);
  const int ty = (p1 == 3) ? y : ((y == 0) ? 55 : y - 1);
  const float* rowp = X + (size_t)n * 256 * 3136 + sp * 3136 + ty * 56;
  ushort_t* orow = xr + y * 56 * 256 + d;
  for (int x = 0; x < 56; ++x) {
    int tx = (p2 == 3) ? x : ((x == 0) ? 55 : x - 1);
    orow[x * 256] = f2b(rowp[tx]);   // 256 lanes -> 512B contiguous store
  }
}

// ================= fused window attention =================================
// Block = (n = XCD via bx&7, window g = bx>>3). 512 threads = 8 waves.
// Fragment conventions (proven in gemm1/attn2/gemm3): A-frag lane(q16,l16)
// holds A[row=tile*16+l16][k=kk*32+quad*8..+8); B-frag same with rows=C-cols;
// C[row=quad*4+r][col=l16].
__global__ __launch_bounds__(512, 1) void k_fused(
    const ushort_t* __restrict__ Xroll, const ushort_t* __restrict__ Aext,
    const ushort_t* __restrict__ Wov3, const float* __restrict__ cvec,
    const float* __restrict__ relL2, float* __restrict__ out) {
  __shared__ ushort_t Xp[64 * FSTR];     // X window tokens [t][d]
  __shared__ ushort_t Msm[64 * FSTR];    // M_h [q][b-local]
  __shared__ ushort_t Tsm[64 * FSTR];    // T^T [q][d]
  __shared__ ushort_t StB[64 * 72];      // wmap [q][p]
  __shared__ float aqsL[8 * 64];
  __shared__ float bpsL[8 * 64];
  __shared__ float relLh[8 * 169];
  __shared__ float mPart[2][64];
  __shared__ float sPart[2][64];

  const int tid = threadIdx.x;
  const int wave = tid >> 6, lane = tid & 63;
  const int quad = lane >> 4, l16 = lane & 15;
  const int n = blockIdx.x & 7, g = blockIdx.x >> 3;
  const int gi = g >> 3, gj = g & 7;
  const ushort_t* Xn = Xroll + (size_t)n * TROWS * 256;
  float* on = out + (size_t)n * 256 * 3136;

  // ---- stage Xp (rows >=49 zeroed) ----
  {
    const int p = tid & 63, cg = tid >> 6;
    if (p < 49) {
      int t = tmap(p, gi, gj);
#pragma unroll
      for (int i = 0; i < 4; ++i)
        *(u16x8*)(&Xp[p * FSTR + (cg * 4 + i) * 8]) =
            *(const u16x8*)(Xn + t * 256 + (cg * 4 + i) * 8);
    } else {
#pragma unroll
      for (int i = 0; i < 4; ++i)
        *(u16x8*)(&Xp[p * FSTR + (cg * 4 + i) * 8]) = (u16x8){0,0,0,0,0,0,0,0};
    }
  }
  for (int i = tid; i < 8 * 169; i += 512) relLh[i] = relL2[i];
  __syncthreads();

  // ---- xfr: PV A-frags (X^T), wave owns d-tiles {wave*2, wave*2+1} ----
  bf16x8 xfr[2][2];
#pragma unroll
  for (int dt = 0; dt < 2; ++dt) {
    const int d = (wave * 2 + dt) * 16 + l16;
#pragma unroll
    for (int kk = 0; kk < 2; ++kk)
#pragma unroll
      for (int j = 0; j < 8; ++j)
        xfr[dt][kk][j] = (short)Xp[(kk * 32 + quad * 8 + j) * FSTR + d];
  }

  // ---- M-step: M_h[t][b] = sum_d G'[h*256+b][d] * Xp[t][d] into Msm ----
  auto m_step = [&](int h) {
    f32x4 macc[2][4];
#pragma unroll
    for (int i = 0; i < 2; ++i)
#pragma unroll
      for (int t = 0; t < 4; ++t) macc[i][t] = (f32x4){0.f, 0.f, 0.f, 0.f};
    const ushort_t* Ah =
        Aext + (size_t)(h * 256 + wave * 32 + l16) * 256 + quad * 8;
#pragma unroll
    for (int kk = 0; kk < 8; ++kk) {
      bf16x8 ga[2];
#pragma unroll
      for (int i = 0; i < 2; ++i)
        ga[i] = *(const bf16x8*)(Ah + i * 16 * 256 + kk * 32);
#pragma unroll
      for (int t = 0; t < 4; ++t) {
        bf16x8 bx_ = *(const bf16x8*)(&Xp[(t * 16 + l16) * FSTR + kk * 32 + quad * 8]);
#pragma unroll
        for (int i = 0; i < 2; ++i)
          macc[i][t] = __builtin_amdgcn_mfma_f32_16x16x32_bf16(ga[i], bx_, macc[i][t], 0, 0, 0);
      }
    }
#pragma unroll
    for (int i = 0; i < 2; ++i)
#pragma unroll
      for (int t = 0; t < 4; ++t)
        *(ushort4*)(&Msm[(t * 16 + l16) * FSTR + wave * 32 + i * 16 + quad * 4]) =
            pack4(macc[i][t]);
  };

  m_step(0);
  if (wave == 0) {
    // Mext: rows 2048..2063 of Aext -> aqs (w1) / bps (w2) per token, f32
    f32x4 eacc[4];
#pragma unroll
    for (int t = 0; t < 4; ++t) eacc[t] = (f32x4){0.f, 0.f, 0.f, 0.f};
    const ushort_t* Ae = Aext + (size_t)(2048 + l16) * 256 + quad * 8;
#pragma unroll
    for (int kk = 0; kk < 8; ++kk) {
      bf16x8 ea = *(const bf16x8*)(Ae + kk * 32);
#pragma unroll
      for (int t = 0; t < 4; ++t) {
        bf16x8 bx_ = *(const bf16x8*)(&Xp[(t * 16 + l16) * FSTR + kk * 32 + quad * 8]);
        eacc[t] = __builtin_amdgcn_mfma_f32_16x16x32_bf16(ea, bx_, eacc[t], 0, 0, 0);
      }
    }
#pragma unroll
    for (int t = 0; t < 4; ++t) {
      const int tok = t * 16 + l16;
#pragma unroll
      for (int r = 0; r < 4; ++r) {
        const int e = quad * 4 + r;
        if (e < 8) aqsL[e * 64 + tok] = eacc[t][r];
        else       bpsL[(e - 8) * 64 + tok] = eacc[t][r];
      }
    }
  }
  __syncthreads();

  // softmax role: wave (wq, wp): q-tile wq, p-half wp (p in [wp*32, wp*32+32))
  const int wq = wave & 3, wp = wave >> 2;
  const int q = wq * 16 + l16;
  const int qq = (q < 49) ? q : 48;
  const int yq = div7(qq), xq = qq - yq * 7;
  const int fq = regof(gi * 7 + yq) * 3 + regof(gj * 7 + xq);

  f32x4 oacc[2][4];
#pragma unroll
  for (int i = 0; i < 2; ++i)
#pragma unroll
    for (int j = 0; j < 4; ++j) oacc[i][j] = (f32x4){0.f, 0.f, 0.f, 0.f};

  for (int h = 0; h < 8; ++h) {
    // ---- S-step: sacc[j] over p-tiles {wp*2+j}, q from l16 ----
    f32x4 sacc[2];
    sacc[0] = (f32x4){0.f, 0.f, 0.f, 0.f};
    sacc[1] = (f32x4){0.f, 0.f, 0.f, 0.f};
#pragma unroll
    for (int kk = 0; kk < 8; ++kk) {
      bf16x8 bfm = *(const bf16x8*)(&Msm[q * FSTR + kk * 32 + quad * 8]);
#pragma unroll
      for (int j = 0; j < 2; ++j) {
        bf16x8 af = *(const bf16x8*)(&Xp[((wp * 2 + j) * 16 + l16) * FSTR + kk * 32 + quad * 8]);
        sacc[j] = __builtin_amdgcn_mfma_f32_16x16x32_bf16(af, bfm, sacc[j], 0, 0, 0);
      }
    }
    // ---- softmax (split over p-halves, LDS combine) ----
    float v[8];
    const float aqv = aqsL[h * 64 + q];
    const float* rel_h = &relLh[h * 169];
    float mw = -1e30f;
#pragma unroll
    for (int j = 0; j < 2; ++j)
#pragma unroll
      for (int r = 0; r < 4; ++r) {
        const int p = (wp * 2 + j) * 16 + quad * 4 + r;
        float val = -1e30f;
        if (p < 49) {
          const int yp = div7(p), xp = p - yp * 7;
          const int fp = regof(gi * 7 + yp) * 3 + regof(gj * 7 + xp);
          val = (sacc[j][r] + aqv + bpsL[h * 64 + p]) * 0.0625f +
                rel_h[(yp - yq + 6) + 13 * (xp - xq + 6)];
          if (fp != fq) val -= 100.f;
        }
        v[j * 4 + r] = val;
        mw = fmaxf(mw, val);
      }
    mw = fmaxf(mw, __shfl_xor(mw, 16));
    mw = fmaxf(mw, __shfl_xor(mw, 32));
    if (lane < 16) mPart[wp][wq * 16 + lane] = mw;
    __syncthreads();                                  // BAR A
    const float mg = fmaxf(mPart[0][q], mPart[1][q]);
    float sw = 0.f;
#pragma unroll
    for (int i2 = 0; i2 < 8; ++i2) { v[i2] = __expf(v[i2] - mg); sw += v[i2]; }
    sw += __shfl_xor(sw, 16);
    sw += __shfl_xor(sw, 32);
    if (lane < 16) sPart[wp][wq * 16 + lane] = sw;
    __syncthreads();                                  // BAR B
    const float inv = 1.f / (sPart[0][q] + sPart[1][q]);
#pragma unroll
    for (int j = 0; j < 2; ++j) {
      ushort4 u;
      u.x = f2b(v[j * 4 + 0] * inv); u.y = f2b(v[j * 4 + 1] * inv);
      u.z = f2b(v[j * 4 + 2] * inv); u.w = f2b(v[j * 4 + 3] * inv);
      *(ushort4*)(&StB[q * 72 + (wp * 2 + j) * 16 + quad * 4]) = u;
    }
    if (h < 7) m_step(h + 1);                         // Msm safe: S reads done
    __syncthreads();                                  // BAR C
    // ---- Wov3 prefetch (L2) for out-step; covered by PV latency ----
    bf16x8 wfr[2][8];
#pragma unroll
    for (int i = 0; i < 2; ++i)
#pragma unroll
      for (int kk = 0; kk < 8; ++kk)
        wfr[i][kk] = *(const bf16x8*)(Wov3 +
            (size_t)(wave * 32 + i * 16 + l16) * 2048 + h * 256 + kk * 32 + quad * 8);
    // ---- PV: T^T[q][d] = sum_p wmap[p][q] * Xp[p][d] ----
#pragma unroll
    for (int qt = 0; qt < 4; ++qt) {
      f32x4 tacc[2];
      tacc[0] = (f32x4){0.f, 0.f, 0.f, 0.f};
      tacc[1] = (f32x4){0.f, 0.f, 0.f, 0.f};
#pragma unroll
      for (int kk = 0; kk < 2; ++kk) {
        bf16x8 bfw = *(const bf16x8*)(&StB[(qt * 16 + l16) * 72 + kk * 32 + quad * 8]);
#pragma unroll
        for (int dt = 0; dt < 2; ++dt)
          tacc[dt] = __builtin_amdgcn_mfma_f32_16x16x32_bf16(xfr[dt][kk], bfw, tacc[dt], 0, 0, 0);
      }
#pragma unroll
      for (int dt = 0; dt < 2; ++dt)
        *(ushort4*)(&Tsm[(qt * 16 + l16) * FSTR + (wave * 2 + dt) * 16 + quad * 4]) =
            pack4(tacc[dt]);
    }
    __syncthreads();                                  // BAR D
    // ---- out-step: oacc[o][q] += Wov3_h[o][d] * T^T[q][d] ----
#pragma unroll
    for (int kk = 0; kk < 8; ++kk) {
#pragma unroll
      for (int qt = 0; qt < 4; ++qt) {
        bf16x8 bfo = *(const bf16x8*)(&Tsm[(qt * 16 + l16) * FSTR + kk * 32 + quad * 8]);
#pragma unroll
        for (int i = 0; i < 2; ++i)
          oacc[i][qt] = __builtin_amdgcn_mfma_f32_16x16x32_bf16(wfr[i][kk], bfo, oacc[i][qt], 0, 0, 0);
      }
    }
    __syncthreads();                                  // BAR E
  }
  // ---- epilogue: out[o][t2] = oacc + cvec ----
#pragma unroll
  for (int i = 0; i < 2; ++i) {
    const int ob = wave * 32 + i * 16 + quad * 4;
    const float4 cv = *(const float4*)(cvec + ob);
#pragma unroll
    for (int qt = 0; qt < 4; ++qt) {
      const int q2 = qt * 16 + l16;
      if (q2 < 49) {
        const int t2 = tmap(q2, gi, gj);
        on[(size_t)(ob + 0) * 3136 + t2] = oacc[i][qt][0] + cv.x;
        on[(size_t)(ob + 1) * 3136 + t2] = oacc[i][qt][1] + cv.y;
        on[(size_t)(ob + 2) * 3136 + t2] = oacc[i][qt][2] + cv.z;
        on[(size_t)(ob + 3) * 3136 + t2] = oacc[i][qt][3] + cv.w;
      }
    }
  }
}

extern "C" void kernel_launch(void* const* d_in, const int* in_sizes, int n_in,
                              void* d_out, int out_size, void* d_ws, size_t ws_size,
                              hipStream_t stream) {
  (void)in_sizes; (void)n_in; (void)out_size; (void)ws_size;
  const float* X  = (const float*)d_in[0];
  const float* Wk = (const float*)d_in[1];
  const float* bk = (const float*)d_in[2];
  const float* Wq = (const float*)d_in[3];
  const float* bq = (const float*)d_in[4];
  const float* Wv = (const float*)d_in[5];
  const float* bv = (const float*)d_in[6];
  const float* Wo = (const float*)d_in[7];
  const float* bo = (const float*)d_in[8];
  const float* rc = (const float*)d_in[9];

  ushort_t* Xroll = (ushort_t*)d_ws;                       // 8*3200*256 u16
  ushort_t* Aext  = Xroll + (size_t)8 * TROWS * 256;       // 2176*256 u16
  ushort_t* Wov3  = Aext + 2176 * 256;                     // 256*2048 u16
  float* fbase = (float*)(Wov3 + 256 * 2048);
  float* cvec  = fbase;         // 256 f32
  float* relL2 = fbase + 256;   // 8*169 f32
  float* out = (float*)d_out;

  k_prep <<<dim3(1290), dim3(256), 0, stream>>>(Wk, Wq, Wo, Wv, bk, bq, bv, bo, rc,
                                                Aext, Wov3, cvec, relL2);
  k_conv <<<dim3(8 * 57), dim3(256), 0, stream>>>(X, Xroll);
  k_fused<<<dim3(512), dim3(512), 0, stream>>>(Xroll, Aext, Wov3, cvec, relL2, out);
}

// Round 6
// 297.407 us; speedup vs baseline: 1.0475x; 1.0262x over previous
//
#include <hip/hip_runtime.h>
#include <hip/hip_bf16.h>

// Swin window MHSA, MI355X, round 12.
//   k_prep : Aext[2176x256]=G'(+w1/w2 rows), Wov3[256x2048], cvec, relL2(+c0)
//   k_conv : X fp32 -> rolled bf16 Xroll[n][3200][256]  (coalesced stores)
//   k_fused: per (n,window) block: M=G'.X (LDS), S=Xp.M, softmax, T^T=X^T.w,
//            out += Wov3_h . T^T.  R12 internals (R11 was LDS/barrier-bound:
//            LDS ~40% of cycles, 5 lockstep barriers/head, MfmaUtil 19%):
//            (a) xb[8][2] reg-hoist of S-step Xp A-frags (invariant over h):
//                -16 LDS reads/head/wave;
//            (b) merged ONE-barrier softmax (each half publishes (m,s) once;
//                scale = exp(mw-mg)/total reconstructed after the barrier);
//            (c) 3 barriers/head instead of 5 (A: softmax exchange, C: StB+
//                Msm(h+1) ready, D: Tsm ready; next-iter BAR A protects Tsm);
//            (d) S-step even/odd-kk split accumulators (4 indep MFMA chains).

#define NBATCH 8
#define TROWS  3200           // padded token rows
#define FSTR   264            // LDS row stride for Xp/Msm/Tsm (bank-spread)

typedef unsigned short ushort_t;
typedef __attribute__((ext_vector_type(8))) short bf16x8;   // 8 bf16 = 4 VGPR
typedef __attribute__((ext_vector_type(8))) unsigned short u16x8;
typedef __attribute__((ext_vector_type(4))) float f32x4;    // MFMA acc

__device__ __forceinline__ float b2f(ushort_t u) {
  union { unsigned int i; float f; } v; v.i = ((unsigned int)u) << 16; return v.f;
}
__device__ __forceinline__ ushort_t f2b(float f) {
  union { float f; unsigned int u; } v; v.f = f;
  unsigned int u = v.u;
  return (ushort_t)((u + 0x7FFFu + ((u >> 16) & 1u)) >> 16);
}
__device__ __forceinline__ int regof(int y) { return (y < 49) ? 0 : ((y < 53) ? 1 : 2); }
__device__ __forceinline__ int div7(int t) { return (t * 37) >> 8; }  // t/7, t<64
__device__ __forceinline__ int tmap(int p, int gi, int gj) {
  int wi = div7(p); return (gi * 7 + wi) * 56 + gj * 7 + (p - wi * 7);
}
__device__ __forceinline__ ushort4 pack4(f32x4 a) {
  ushort4 u; u.x = f2b(a[0]); u.y = f2b(a[1]); u.z = f2b(a[2]); u.w = f2b(a[3]);
  return u;
}

// ================= prep (unchanged) =================
__global__ void k_prep(const float* __restrict__ Wk, const float* __restrict__ Wq,
                       const float* __restrict__ Wo, const float* __restrict__ Wv,
                       const float* __restrict__ bk, const float* __restrict__ bq,
                       const float* __restrict__ bv, const float* __restrict__ bo,
                       const float* __restrict__ relc,
                       ushort_t* __restrict__ Aext, ushort_t* __restrict__ Wov3,
                       float* __restrict__ cvec, float* __restrict__ relL2) {
  __shared__ float red[8];
  int blk = blockIdx.x, t = threadIdx.x;
  if (blk < 512) {
    int h = blk >> 6, b0 = (blk & 63) << 2, a = t;
    const float* wkh = Wk + h * 65536;
    const float* wqh = Wq + h * 65536;
    float a0 = 0.f, a1 = 0.f, a2 = 0.f, a3 = 0.f;
    for (int dd = 0; dd < 256; ++dd) {
      float wk = wkh[dd * 256 + a];
      float4 w4 = *(const float4*)(wqh + dd * 256 + b0);
      a0 += wk * w4.x; a1 += wk * w4.y; a2 += wk * w4.z; a3 += wk * w4.w;
    }
    ushort4 u; u.x = f2b(a0); u.y = f2b(a1); u.z = f2b(a2); u.w = f2b(a3);
    *(ushort4*)(Aext + (h * 256 + a) * 256 + b0) = u;
  } else if (blk < 1024) {
    int bb = blk - 512;
    int h = bb >> 6, o0 = (bb & 63) << 2, d = t;
    float a0 = 0.f, a1 = 0.f, a2 = 0.f, a3 = 0.f;
    for (int dd = 0; dd < 256; ++dd) {
      float wv = Wv[(h * 256 + dd) * 256 + d];
      a0 += Wo[(o0 + 0) * 2048 + h * 256 + dd] * wv;
      a1 += Wo[(o0 + 1) * 2048 + h * 256 + dd] * wv;
      a2 += Wo[(o0 + 2) * 2048 + h * 256 + dd] * wv;
      a3 += Wo[(o0 + 3) * 2048 + h * 256 + dd] * wv;
    }
    Wov3[(o0 + 0) * 2048 + h * 256 + d] = f2b(a0);
    Wov3[(o0 + 1) * 2048 + h * 256 + d] = f2b(a1);
    Wov3[(o0 + 2) * 2048 + h * 256 + d] = f2b(a2);
    Wov3[(o0 + 3) * 2048 + h * 256 + d] = f2b(a3);
  } else if (blk < 1032) {
    int h = blk - 1024;
    float s1 = 0.f, s2 = 0.f;
    for (int dd = 0; dd < 256; ++dd) {
      s1 += bk[h * 256 + dd] * Wq[(h * 256 + dd) * 256 + t];
      s2 += bq[h * 256 + dd] * Wk[(h * 256 + dd) * 256 + t];
    }
    Aext[(2048 + h) * 256 + t] = f2b(s1);
    Aext[(2056 + h) * 256 + t] = f2b(s2);
  } else if (blk == 1032) {
    for (int i = t; i < 112 * 256 / 8; i += 256)
      *(u16x8*)(Aext + 2064 * 256 + i * 8) = (u16x8){0,0,0,0,0,0,0,0};
  } else if (blk < 1289) {
    int o = blk - 1033;
    const float* wob = Wo + o * 2048;
    float acc = 0.f;
#pragma unroll
    for (int j = 0; j < 8; ++j) acc += wob[j * 256 + t] * bv[j * 256 + t];
#pragma unroll
    for (int s = 1; s < 64; s <<= 1) acc += __shfl_xor(acc, s);
    if ((t & 63) == 0) red[t >> 6] = acc;
    __syncthreads();
    if (t == 0) cvec[o] = bo[o] + red[0] + red[1] + red[2] + red[3];
  } else {
    if (t < 8) {
      float c = 0.f;
      for (int dd = 0; dd < 256; ++dd) c += bk[t * 256 + dd] * bq[t * 256 + dd];
      red[t] = c * 0.0625f;
    }
    __syncthreads();
    for (int i = t; i < 8 * 169; i += 256) {
      int h = i / 169, idx = i - h * 169;
      relL2[i] = relc[idx * 8 + h] + red[h];
    }
  }
}

// ================= conv: rolled gather, coalesced bf16 stores =============
__global__ void k_conv(const float* __restrict__ X, ushort_t* __restrict__ Xroll) {
  const int n = blockIdx.x / 57, y = blockIdx.x % 57;
  ushort_t* xr = Xroll + (size_t)n * TROWS * 256;
  const int d = threadIdx.x;
  if (y == 56) {  // zero pad rows 3136..3199
    for (int i = d; i < 64 * 256 / 8; i += 256)
      *(u16x8*)(xr + 3136 * 256 + i * 8) = (u16x8){0,0,0,0,0,0,0,0};
    return;
  }
  const int c = d >> 4, p1 = (d >> 2) & 3, p2 = d & 3;
  const int sp = c * 16 + (((p1 + 1) & 3) << 2) + ((p2 + 1) & 3);
  const int ty = (p1 == 3) ? y : ((y == 0) ? 55 : y - 1);
  const float* rowp = X + (size_t)n * 256 * 3136 + sp * 3136 + ty * 56;
  ushort_t* orow = xr + y * 56 * 256 + d;
  for (int x = 0; x < 56; ++x) {
    int tx = (p2 == 3) ? x : ((x == 0) ? 55 : x - 1);
    orow[x * 256] = f2b(rowp[tx]);   // 256 lanes -> 512B contiguous store
  }
}

// ================= fused window attention =================================
// Block = (n = XCD via bx&7, window g = bx>>3). 512 threads = 8 waves.
__global__ __launch_bounds__(512, 1) void k_fused(
    const ushort_t* __restrict__ Xroll, const ushort_t* __restrict__ Aext,
    const ushort_t* __restrict__ Wov3, const float* __restrict__ cvec,
    const float* __restrict__ relL2, float* __restrict__ out) {
  __shared__ ushort_t Xp[64 * FSTR];     // X window tokens [t][d]
  __shared__ ushort_t Msm[64 * FSTR];    // M_h [q][b-local]
  __shared__ ushort_t Tsm[64 * FSTR];    // T^T [q][d]
  __shared__ ushort_t StB[64 * 72];      // wmap [q][p]
  __shared__ float aqsL[8 * 64];
  __shared__ float bpsL[8 * 64];
  __shared__ float relLh[8 * 169];
  __shared__ float mPart[2][64];
  __shared__ float sPart[2][64];

  const int tid = threadIdx.x;
  const int wave = tid >> 6, lane = tid & 63;
  const int quad = lane >> 4, l16 = lane & 15;
  const int n = blockIdx.x & 7, g = blockIdx.x >> 3;
  const int gi = g >> 3, gj = g & 7;
  const ushort_t* Xn = Xroll + (size_t)n * TROWS * 256;
  float* on = out + (size_t)n * 256 * 3136;

  // ---- stage Xp (rows >=49 zeroed) ----
  {
    const int p = tid & 63, cg = tid >> 6;
    if (p < 49) {
      int t = tmap(p, gi, gj);
#pragma unroll
      for (int i = 0; i < 4; ++i)
        *(u16x8*)(&Xp[p * FSTR + (cg * 4 + i) * 8]) =
            *(const u16x8*)(Xn + t * 256 + (cg * 4 + i) * 8);
    } else {
#pragma unroll
      for (int i = 0; i < 4; ++i)
        *(u16x8*)(&Xp[p * FSTR + (cg * 4 + i) * 8]) = (u16x8){0,0,0,0,0,0,0,0};
    }
  }
  for (int i = tid; i < 8 * 169; i += 512) relLh[i] = relL2[i];
  __syncthreads();

  const int wp = wave >> 2;   // p-half for S/softmax
  const int wq = wave & 3;    // q-tile for S/softmax

  // ---- xb: S-step Xp A-frags (tiles 2wp, 2wp+1), invariant over h ----
  bf16x8 xb[8][2];
#pragma unroll
  for (int kk = 0; kk < 8; ++kk)
#pragma unroll
    for (int j = 0; j < 2; ++j)
      xb[kk][j] = *(const bf16x8*)(&Xp[((wp * 2 + j) * 16 + l16) * FSTR + kk * 32 + quad * 8]);

  // ---- xfr: PV A-frags (X^T), wave owns d-tiles {wave*2, wave*2+1} ----
  bf16x8 xfr[2][2];
#pragma unroll
  for (int dt = 0; dt < 2; ++dt) {
    const int d = (wave * 2 + dt) * 16 + l16;
#pragma unroll
    for (int kk = 0; kk < 2; ++kk)
#pragma unroll
      for (int j = 0; j < 8; ++j)
        xfr[dt][kk][j] = (short)Xp[(kk * 32 + quad * 8 + j) * FSTR + d];
  }

  // ---- M-step: M_h[t][b] = sum_d G'[h*256+b][d] * Xp[t][d] into Msm ----
  auto m_step = [&](int h) {
    f32x4 macc[2][4];
#pragma unroll
    for (int i = 0; i < 2; ++i)
#pragma unroll
      for (int t = 0; t < 4; ++t) macc[i][t] = (f32x4){0.f, 0.f, 0.f, 0.f};
    const ushort_t* Ah =
        Aext + (size_t)(h * 256 + wave * 32 + l16) * 256 + quad * 8;
#pragma unroll
    for (int kk = 0; kk < 8; ++kk) {
      bf16x8 ga[2];
#pragma unroll
      for (int i = 0; i < 2; ++i)
        ga[i] = *(const bf16x8*)(Ah + i * 16 * 256 + kk * 32);
#pragma unroll
      for (int t = 0; t < 4; ++t) {
        bf16x8 bx_ = *(const bf16x8*)(&Xp[(t * 16 + l16) * FSTR + kk * 32 + quad * 8]);
#pragma unroll
        for (int i = 0; i < 2; ++i)
          macc[i][t] = __builtin_amdgcn_mfma_f32_16x16x32_bf16(ga[i], bx_, macc[i][t], 0, 0, 0);
      }
    }
#pragma unroll
    for (int i = 0; i < 2; ++i)
#pragma unroll
      for (int t = 0; t < 4; ++t)
        *(ushort4*)(&Msm[(t * 16 + l16) * FSTR + wave * 32 + i * 16 + quad * 4]) =
            pack4(macc[i][t]);
  };

  m_step(0);
  if (wave == 0) {
    // Mext: rows 2048..2063 of Aext -> aqs (w1) / bps (w2) per token, f32
    f32x4 eacc[4];
#pragma unroll
    for (int t = 0; t < 4; ++t) eacc[t] = (f32x4){0.f, 0.f, 0.f, 0.f};
    const ushort_t* Ae = Aext + (size_t)(2048 + l16) * 256 + quad * 8;
#pragma unroll
    for (int kk = 0; kk < 8; ++kk) {
      bf16x8 ea = *(const bf16x8*)(Ae + kk * 32);
#pragma unroll
      for (int t = 0; t < 4; ++t) {
        bf16x8 bx_ = *(const bf16x8*)(&Xp[(t * 16 + l16) * FSTR + kk * 32 + quad * 8]);
        eacc[t] = __builtin_amdgcn_mfma_f32_16x16x32_bf16(ea, bx_, eacc[t], 0, 0, 0);
      }
    }
#pragma unroll
    for (int t = 0; t < 4; ++t) {
      const int tok = t * 16 + l16;
#pragma unroll
      for (int r = 0; r < 4; ++r) {
        const int e = quad * 4 + r;
        if (e < 8) aqsL[e * 64 + tok] = eacc[t][r];
        else       bpsL[(e - 8) * 64 + tok] = eacc[t][r];
      }
    }
  }
  __syncthreads();

  const int q = wq * 16 + l16;
  const int qq = (q < 49) ? q : 48;
  const int yq = div7(qq), xq = qq - yq * 7;
  const int fq = regof(gi * 7 + yq) * 3 + regof(gj * 7 + xq);

  f32x4 oacc[2][4];
#pragma unroll
  for (int i = 0; i < 2; ++i)
#pragma unroll
    for (int j = 0; j < 4; ++j) oacc[i][j] = (f32x4){0.f, 0.f, 0.f, 0.f};

  for (int h = 0; h < 8; ++h) {
    // ---- S-step: even/odd-kk split accumulators (4 indep chains) ----
    f32x4 sa0[2], sa1[2];
    sa0[0] = (f32x4){0.f,0.f,0.f,0.f}; sa0[1] = (f32x4){0.f,0.f,0.f,0.f};
    sa1[0] = (f32x4){0.f,0.f,0.f,0.f}; sa1[1] = (f32x4){0.f,0.f,0.f,0.f};
#pragma unroll
    for (int kk = 0; kk < 8; kk += 2) {
      bf16x8 bfm0 = *(const bf16x8*)(&Msm[q * FSTR + kk * 32 + quad * 8]);
      bf16x8 bfm1 = *(const bf16x8*)(&Msm[q * FSTR + (kk + 1) * 32 + quad * 8]);
#pragma unroll
      for (int j = 0; j < 2; ++j) {
        sa0[j] = __builtin_amdgcn_mfma_f32_16x16x32_bf16(xb[kk][j], bfm0, sa0[j], 0, 0, 0);
        sa1[j] = __builtin_amdgcn_mfma_f32_16x16x32_bf16(xb[kk + 1][j], bfm1, sa1[j], 0, 0, 0);
      }
    }
    // ---- softmax part 1 (own p-half) ----
    float v[8], ew[8];
    const float aqv = aqsL[h * 64 + q];
    const float* rel_h = &relLh[h * 169];
    float mw = -1e30f;
#pragma unroll
    for (int j = 0; j < 2; ++j)
#pragma unroll
      for (int r = 0; r < 4; ++r) {
        const int p = (wp * 2 + j) * 16 + quad * 4 + r;
        float val = -1e30f;
        if (p < 49) {
          const int yp = div7(p), xp = p - yp * 7;
          const int fp = regof(gi * 7 + yp) * 3 + regof(gj * 7 + xp);
          val = (sa0[j][r] + sa1[j][r] + aqv + bpsL[h * 64 + p]) * 0.0625f +
                rel_h[(yp - yq + 6) + 13 * (xp - xq + 6)];
          if (fp != fq) val -= 100.f;
        }
        v[j * 4 + r] = val;
        mw = fmaxf(mw, val);
      }
    mw = fmaxf(mw, __shfl_xor(mw, 16));
    mw = fmaxf(mw, __shfl_xor(mw, 32));
    float sw = 0.f;
#pragma unroll
    for (int i2 = 0; i2 < 8; ++i2) { ew[i2] = __expf(v[i2] - mw); sw += ew[i2]; }
    sw += __shfl_xor(sw, 16);
    sw += __shfl_xor(sw, 32);
    if (lane < 16) { mPart[wp][wq * 16 + lane] = mw; sPart[wp][wq * 16 + lane] = sw; }
    __syncthreads();                                  // BAR A
    // ---- softmax part 2: combine halves, write StB ----
    {
      const float m0 = mPart[0][q], m1 = mPart[1][q];
      const float s0 = sPart[0][q], s1 = sPart[1][q];
      const float mg = fmaxf(m0, m1);
      const float tot = s0 * __expf(m0 - mg) + s1 * __expf(m1 - mg);
      const float scale = __expf(mw - mg) / tot;
#pragma unroll
      for (int j = 0; j < 2; ++j) {
        ushort4 u;
        u.x = f2b(ew[j * 4 + 0] * scale); u.y = f2b(ew[j * 4 + 1] * scale);
        u.z = f2b(ew[j * 4 + 2] * scale); u.w = f2b(ew[j * 4 + 3] * scale);
        *(ushort4*)(&StB[q * 72 + (wp * 2 + j) * 16 + quad * 4]) = u;
      }
    }
    if (h < 7) m_step(h + 1);   // Msm safe: all waves passed BAR A (S reads done)
    __syncthreads();                                  // BAR C
    // ---- Wov3 prefetch (L2) for out-step; latency hidden under PV ----
    bf16x8 wfr[2][8];
#pragma unroll
    for (int i = 0; i < 2; ++i)
#pragma unroll
      for (int kk = 0; kk < 8; ++kk)
        wfr[i][kk] = *(const bf16x8*)(Wov3 +
            (size_t)(wave * 32 + i * 16 + l16) * 2048 + h * 256 + kk * 32 + quad * 8);
    // ---- PV: T^T[q][d] = sum_p wmap[p][q] * Xp[p][d] ----
#pragma unroll
    for (int qt = 0; qt < 4; ++qt) {
      f32x4 tacc[2];
      tacc[0] = (f32x4){0.f, 0.f, 0.f, 0.f};
      tacc[1] = (f32x4){0.f, 0.f, 0.f, 0.f};
#pragma unroll
      for (int kk = 0; kk < 2; ++kk) {
        bf16x8 bfw = *(const bf16x8*)(&StB[(qt * 16 + l16) * 72 + kk * 32 + quad * 8]);
#pragma unroll
        for (int dt = 0; dt < 2; ++dt)
          tacc[dt] = __builtin_amdgcn_mfma_f32_16x16x32_bf16(xfr[dt][kk], bfw, tacc[dt], 0, 0, 0);
      }
#pragma unroll
      for (int dt = 0; dt < 2; ++dt)
        *(ushort4*)(&Tsm[(qt * 16 + l16) * FSTR + (wave * 2 + dt) * 16 + quad * 4]) =
            pack4(tacc[dt]);
    }
    __syncthreads();                                  // BAR D
    // ---- out-step: oacc[o][q] += Wov3_h[o][d] * T^T[q][d] ----
#pragma unroll
    for (int kk = 0; kk < 8; ++kk) {
#pragma unroll
      for (int qt = 0; qt < 4; ++qt) {
        bf16x8 bfo = *(const bf16x8*)(&Tsm[(qt * 16 + l16) * FSTR + kk * 32 + quad * 8]);
#pragma unroll
        for (int i = 0; i < 2; ++i)
          oacc[i][qt] = __builtin_amdgcn_mfma_f32_16x16x32_bf16(wfr[i][kk], bfo, oacc[i][qt], 0, 0, 0);
      }
    }
    // no barrier: next iteration's BAR A orders Tsm reuse (PV(h+1) is
    // after BAR C(h+1); every wave's out(h) precedes its BAR A(h+1))
  }
  // ---- epilogue: out[o][t2] = oacc + cvec ----
#pragma unroll
  for (int i = 0; i < 2; ++i) {
    const int ob = wave * 32 + i * 16 + quad * 4;
    const float4 cv = *(const float4*)(cvec + ob);
#pragma unroll
    for (int qt = 0; qt < 4; ++qt) {
      const int q2 = qt * 16 + l16;
      if (q2 < 49) {
        const int t2 = tmap(q2, gi, gj);
        on[(size_t)(ob + 0) * 3136 + t2] = oacc[i][qt][0] + cv.x;
        on[(size_t)(ob + 1) * 3136 + t2] = oacc[i][qt][1] + cv.y;
        on[(size_t)(ob + 2) * 3136 + t2] = oacc[i][qt][2] + cv.z;
        on[(size_t)(ob + 3) * 3136 + t2] = oacc[i][qt][3] + cv.w;
      }
    }
  }
}

extern "C" void kernel_launch(void* const* d_in, const int* in_sizes, int n_in,
                              void* d_out, int out_size, void* d_ws, size_t ws_size,
                              hipStream_t stream) {
  (void)in_sizes; (void)n_in; (void)out_size; (void)ws_size;
  const float* X  = (const float*)d_in[0];
  const float* Wk = (const float*)d_in[1];
  const float* bk = (const float*)d_in[2];
  const float* Wq = (const float*)d_in[3];
  const float* bq = (const float*)d_in[4];
  const float* Wv = (const float*)d_in[5];
  const float* bv = (const float*)d_in[6];
  const float* Wo = (const float*)d_in[7];
  const float* bo = (const float*)d_in[8];
  const float* rc = (const float*)d_in[9];

  ushort_t* Xroll = (ushort_t*)d_ws;                       // 8*3200*256 u16
  ushort_t* Aext  = Xroll + (size_t)8 * TROWS * 256;       // 2176*256 u16
  ushort_t* Wov3  = Aext + 2176 * 256;                     // 256*2048 u16
  float* fbase = (float*)(Wov3 + 256 * 2048);
  float* cvec  = fbase;         // 256 f32
  float* relL2 = fbase + 256;   // 8*169 f32
  float* out = (float*)d_out;

  k_prep <<<dim3(1290), dim3(256), 0, stream>>>(Wk, Wq, Wo, Wv, bk, bq, bv, bo, rc,
                                                Aext, Wov3, cvec, relL2);
  k_conv <<<dim3(8 * 57), dim3(256), 0, stream>>>(X, Xroll);
  k_fused<<<dim3(512), dim3(512), 0, stream>>>(Xroll, Aext, Wov3, cvec, relL2, out);
}